// Round 3
// baseline (521.288 us; speedup 1.0000x reference)
//
#include <hip/hip_runtime.h>

// MPS tensor-train classifier, B=16384, D=784, BOND=5, OUT=10.
//
// Round-6: 2-rows/lane (halves broadcast LDS reads per row) done WITHOUT
// round-5's two failure modes:
//   (a) spills: state cut to ~150 floats (in-place matmul, no T frag) and
//       __launch_bounds__(768,3) -> 170 VGPR budget (round-5: ~200 floats
//       vs 128 VGPRs -> 22 MB scratch writes).
//   (b) occupancy: 12 waves/CU (3/SIMD) vs round-5's 8.
// Structure: 256 blocks x 768 thr; block = {row-group g (128 rows), half h}.
//   wave 0:   vector chain, 19 pairs + boundary sites.
//   waves 1..11: 16-pair matrix products (in-place 5x5).
//   combine: 2 phases (6+5 matbuf slots), 3 barriers.
// h=0: carry0+site0+pairs 0..18, slots cover 19..194 -> vL.
// h=1: vlast+site781+pairs 389..371 desc (transposed storage), slots cover
//      195..370 -> wR = M_s...applied descending.
// Stash: vL -> out-flat[0:81920), wR -> out-flat[81920:163840) (disjoint
// lines, single writer each). finish1: res=vL.wR -> ws (pk region, dead).
// finish2: out = res*fc_w + fc_b.

typedef float v4f __attribute__((ext_vector_type(4)));
typedef float v2f __attribute__((ext_vector_type(2)));

constexpr int Bn     = 16384;
constexpr int Dn     = 784;
constexpr int NOUT   = 10;
constexpr int NPAIR  = 390;   // pairs cover sites 1..780
constexpr int PVEC   = 19;    // pairs per vector wave
constexpr int NMAT   = 11;    // matrix waves per half
constexpr int PMAT   = 16;    // pairs per matrix wave
constexpr int RHP0   = 195;   // right half first pair
constexpr int BWD_P0 = 371;   // pairs >= this stored transposed (bwd vec)
constexpr int PAIR_F = 100;   // floats per pair block: 4 mats x 25
constexpr int PAIR_V = 25;    // v4f per pair block
constexpr int WROFF  = Bn * 5; // wR stash offset (floats) in out
// per-pair layout (100 floats), q = 0..3 (1, xa, xb, xa*xb coefficient):
//   rows:  q*20 + l*4 + r   (l=0..4, r=0..3)
//   col4:  80 + q*4 + l     (l=0..3)
//   (4,4): 96 + q           (all four c44 in ONE v4f -> 1 read)

__device__ __forceinline__ v4f splat4(float x) { v4f v = {x, x, x, x}; return v; }
__device__ __forceinline__ v4f fma4(v4f a, v4f b, v4f c) {
    return __builtin_elementwise_fma(a, b, c);
}

struct Frag { v4f r[5]; float c4[5]; };          // 5x5 running product
struct CMat { v4f row[5]; v4f c4v; float c44; }; // 5x5 pair matrix

// build C for TWO rows from ONE pass over the pair block (25 ds_read_b128)
__device__ __forceinline__ void build_C2(const float* s, v2f xA, v2f xB,
                                         CMat& CA, CMat& CB) {
    const float aA = xA[0], bA = xA[1], pA = aA * bA;
    const float aB = xB[0], bB = xB[1], pB = aB * bB;
    const v4f vaA = splat4(aA), vbA = splat4(bA), vpA = splat4(pA);
    const v4f vaB = splat4(aB), vbB = splat4(bB), vpB = splat4(pB);
    const v4f* s4 = (const v4f*)s;
#pragma unroll
    for (int l = 0; l < 5; ++l) {
        v4f q0 = s4[l], q1 = s4[5 + l], q2 = s4[10 + l], q3 = s4[15 + l];
        CA.row[l] = fma4(vpA, q3, fma4(vbA, q2, fma4(vaA, q1, q0)));
        CB.row[l] = fma4(vpB, q3, fma4(vbB, q2, fma4(vaB, q1, q0)));
    }
    {
        v4f q0 = s4[20], q1 = s4[21], q2 = s4[22], q3 = s4[23];
        CA.c4v = fma4(vpA, q3, fma4(vbA, q2, fma4(vaA, q1, q0)));
        CB.c4v = fma4(vpB, q3, fma4(vbB, q2, fma4(vaB, q1, q0)));
    }
    {
        v4f q = s4[24];   // {c44 of q0, q1, q2, q3}
        CA.c44 = fmaf(pA, q[3], fmaf(bA, q[2], fmaf(aA, q[1], q[0])));
        CB.c44 = fmaf(pB, q[3], fmaf(bB, q[2], fmaf(aB, q[1], q[0])));
    }
}

// M = M @ C, in place (output row i depends only on input row i)
__device__ __forceinline__ void matstep(Frag& M, const CMat& C) {
#pragma unroll
    for (int i = 0; i < 5; ++i) {
        v4f acc  = splat4(M.r[i][0]) * C.row[0];
        float a4 = M.r[i][0] * C.c4v[0];
#pragma unroll
        for (int l = 1; l < 4; ++l) {
            acc = fma4(splat4(M.r[i][l]), C.row[l], acc);
            a4  = fmaf(M.r[i][l], C.c4v[l], a4);
        }
        acc = fma4(splat4(M.c4[i]), C.row[4], acc);
        a4  = fmaf(M.c4[i], C.c44, a4);
        M.r[i] = acc; M.c4[i] = a4;
    }
}

// c' = c @ C   (row vector)
__device__ __forceinline__ void vecstep(v4f& cv, float& c4, const CMat& C) {
    v4f acc  = splat4(cv[0]) * C.row[0];
    float a4 = cv[0] * C.c4v[0];
#pragma unroll
    for (int l = 1; l < 4; ++l) {
        acc = fma4(splat4(cv[l]), C.row[l], acc);
        a4  = fmaf(cv[l], C.c4v[l], a4);
    }
    acc = fma4(splat4(c4), C.row[4], acc);
    a4  = fmaf(c4, C.c44, a4);
    cv = acc; c4 = a4;
}

// staging: 4-pair chunk = 100 v4f = 1600 B (matrix waves)
__device__ __forceinline__ void sload(const v4f* src, v4f& a, v4f& b, int lane) {
    a = src[lane];
    if (lane < 36) b = src[64 + lane];
}
__device__ __forceinline__ void swrite(v4f* dst, v4f a, v4f b, int lane) {
    dst[lane] = a;
    if (lane < 36) dst[64 + lane] = b;
}
// staging: 2-pair chunk = 50 v4f = 800 B (vector waves)
__device__ __forceinline__ void sload50(const v4f* src, v4f& a, int lane) {
    if (lane < 50) a = src[lane];
}
__device__ __forceinline__ void swrite50(v4f* dst, v4f a, int lane) {
    if (lane < 50) dst[lane] = a;
}

// ---- prepack: build pair blocks (transposed for p >= BWD_P0) ----
// cores_mid element (m,l,i,k) at (m*5+l)*10 + i*5 + k
__global__ void prepack_pairs(const float* __restrict__ cm, float* __restrict__ pk)
{
    int idx = blockIdx.x * 256 + threadIdx.x;
    if (idx >= NPAIR * 100) return;
    int p = idx / 100, rest = idx - p * 100;
    int q = rest / 25, e = rest - q * 25;
    int l = e / 5, r = e - l * 5;
    int m1 = 2 * p + 1, m2 = 2 * p + 2;
    const float* L = cm + (size_t)(m1 * 5 + l) * 10;
    float acc = 0.f;
#pragma unroll
    for (int k = 0; k < 5; ++k) {
        float Lk = (q & 1) ? (L[5 + k] - L[k]) : L[k];
        const float* R = cm + (size_t)(m2 * 5 + k) * 10;
        float Rk = (q & 2) ? (R[5 + r] - R[r]) : R[r];
        acc = fmaf(Lk, Rk, acc);
    }
    int wl = l, wr = r;
    if (p >= BWD_P0) { wl = r; wr = l; }   // store C^T for bwd vec wave
    int off;
    if (wr < 4)      off = q * 20 + wl * 4 + wr;
    else if (wl < 4) off = 80 + q * 4 + wl;
    else             off = 96 + q;
    pk[(size_t)p * PAIR_F + off] = acc;
}

__global__ __launch_bounds__(768, 3)
void mps_half_kernel(const float* __restrict__ x,          // [B, D]
                     const float* __restrict__ core_first, // [2,5]
                     const float* __restrict__ cores_mid,  // [782,5,2,5]
                     const float* __restrict__ core_last,  // [5,2]
                     const float* __restrict__ pk,         // [390][100]
                     float* __restrict__ out)              // [B,10] used as stash
{
    __shared__ v4f   pkbuf[12][2][100];   // 38.4 KB double-buffered chunks
    __shared__ float matbuf[6][25][128];  // 76.8 KB combine matrices

    const int lane = threadIdx.x & 63;
    const int wave = threadIdx.x >> 6;    // 0..11
    const int g    = blockIdx.x >> 1;
    const int h    = blockIdx.x & 1;
    const int rowA = g * 128 + lane;
    const int rowB = rowA + 64;
    const v2f* __restrict__ xA2 = (const v2f*)(x + (size_t)rowA * Dn);
    const v2f* __restrict__ xB2 = (const v2f*)(x + (size_t)rowB * Dn);
    const v4f* __restrict__ pk4 = (const v4f*)pk;

    v4f* buf0 = &pkbuf[wave][0][0];
    v4f* buf1 = &pkbuf[wave][1][0];

    if (wave != 0) {
        // ---- matrix wave: 16 pairs, 4 chunks of 4, 2 rows/lane, in-place ----
        const int s  = wave - 1;
        const int p0 = (h == 0 ? PVEC : RHP0) + PMAT * s;
        v4f sa, sb;
        sload(pk4 + (size_t)p0 * PAIR_V, sa, sb, lane);
        swrite(buf0, sa, sb, lane);
        sload(pk4 + (size_t)(p0 + 4) * PAIR_V, sa, sb, lane);
        v2f cA0 = xA2[p0 + 1], cA1 = xA2[p0 + 2], cA2 = xA2[p0 + 3], cA3 = xA2[p0 + 4];
        v2f cB0 = xB2[p0 + 1], cB1 = xB2[p0 + 2], cB2 = xB2[p0 + 3], cB3 = xB2[p0 + 4];

        Frag MA, MB;
        MA.r[0] = {1,0,0,0}; MA.r[1] = {0,1,0,0}; MA.r[2] = {0,0,1,0};
        MA.r[3] = {0,0,0,1}; MA.r[4] = {0,0,0,0};
        MA.c4[0] = 0; MA.c4[1] = 0; MA.c4[2] = 0; MA.c4[3] = 0; MA.c4[4] = 1;
        MB = MA;

#pragma unroll 1
        for (int c = 0; c < 4; ++c) {
            v4f* wb = (c & 1) ? buf0 : buf1;
            const float* rb = (const float*)((c & 1) ? buf1 : buf0);
            swrite(wb, sa, sb, lane);                      // chunk c+1 -> LDS
            int ns = p0 + 4 * (c + 2);                     // next-next chunk
            if (ns > NPAIR - 4) ns = NPAIR - 4;
            sload(pk4 + (size_t)ns * PAIR_V, sa, sb, lane);
            const int pn = p0 + 4 * (c + 1);               // x prefetch
            v2f nA0 = xA2[pn + 1], nA1 = xA2[pn + 2], nA2 = xA2[pn + 3], nA3 = xA2[pn + 4];
            v2f nB0 = xB2[pn + 1], nB1 = xB2[pn + 2], nB2 = xB2[pn + 3], nB3 = xB2[pn + 4];
            CMat CA, CB;
            build_C2(rb + 0 * PAIR_F, cA0, cB0, CA, CB);
            matstep(MA, CA); matstep(MB, CB);
            build_C2(rb + 1 * PAIR_F, cA1, cB1, CA, CB);
            matstep(MA, CA); matstep(MB, CB);
            build_C2(rb + 2 * PAIR_F, cA2, cB2, CA, CB);
            matstep(MA, CA); matstep(MB, CB);
            build_C2(rb + 3 * PAIR_F, cA3, cB3, CA, CB);
            matstep(MA, CA); matstep(MB, CB);
            cA0 = nA0; cA1 = nA1; cA2 = nA2; cA3 = nA3;
            cB0 = nB0; cB1 = nB1; cB2 = nB2; cB3 = nB3;
        }

        const bool ph1 = (h == 0) ? (s < 6) : (s >= 5);
        const int  k   = ph1 ? ((h == 0) ? s : 10 - s)
                             : ((h == 0) ? s - 6 : 4 - s);
        if (ph1) {
#pragma unroll
            for (int i = 0; i < 5; ++i) {
#pragma unroll
                for (int r = 0; r < 4; ++r) {
                    matbuf[k][i * 5 + r][lane]      = MA.r[i][r];
                    matbuf[k][i * 5 + r][lane + 64] = MB.r[i][r];
                }
                matbuf[k][i * 5 + 4][lane]      = MA.c4[i];
                matbuf[k][i * 5 + 4][lane + 64] = MB.c4[i];
            }
        }
        __syncthreads();   // b1: phase-1 slots ready
        __syncthreads();   // b2: vec finished reading phase-1
        if (!ph1) {
#pragma unroll
            for (int i = 0; i < 5; ++i) {
#pragma unroll
                for (int r = 0; r < 4; ++r) {
                    matbuf[k][i * 5 + r][lane]      = MA.r[i][r];
                    matbuf[k][i * 5 + r][lane + 64] = MB.r[i][r];
                }
                matbuf[k][i * 5 + 4][lane]      = MA.c4[i];
                matbuf[k][i * 5 + 4][lane + 64] = MB.c4[i];
            }
        }
        __syncthreads();   // b3: phase-2 slots ready
    } else if (h == 0) {
        // ---- left vector wave: carry0, site 0, pairs 0..18, combine ----
        v2f xA01 = xA2[0], xB01 = xB2[0];
        float clA[5], clB[5], cnA[5], cnB[5];
#pragma unroll
        for (int r = 0; r < 5; ++r) {
            float d = core_first[5 + r] - core_first[r];
            clA[r] = fmaf(xA01[0], d, core_first[r]);
            clB[r] = fmaf(xB01[0], d, core_first[r]);
        }
        const float* cm0 = cores_mid;                      // site 0
#pragma unroll
        for (int r = 0; r < 5; ++r) {
            float aA = 0.f, aB = 0.f;
#pragma unroll
            for (int l = 0; l < 5; ++l) {
                float base = cm0[l * 10 + r], d = cm0[l * 10 + 5 + r] - base;
                aA = fmaf(clA[l], fmaf(xA01[1], d, base), aA);
                aB = fmaf(clB[l], fmaf(xB01[1], d, base), aB);
            }
            cnA[r] = aA; cnB[r] = aB;
        }
        v4f cvA = {cnA[0], cnA[1], cnA[2], cnA[3]};
        v4f cvB = {cnB[0], cnB[1], cnB[2], cnB[3]};
        float c4A = cnA[4], c4B = cnB[4];

        v4f sa;
        sload50(pk4 + 0, sa, lane);
        swrite50(buf0, sa, lane);
        sload50(pk4 + (size_t)2 * PAIR_V, sa, lane);
        v2f cA0 = xA2[1], cA1 = xA2[2];
        v2f cB0 = xB2[1], cB1 = xB2[2];

#pragma unroll 1
        for (int c = 0; c < 10; ++c) {                     // 9x2 + 1x1 = 19 pairs
            v4f* wb = (c & 1) ? buf0 : buf1;
            const float* rb = (const float*)((c & 1) ? buf1 : buf0);
            swrite50(wb, sa, lane);
            int ns = 2 * (c + 2);                          // <= 22, in bounds
            sload50(pk4 + (size_t)ns * PAIR_V, sa, lane);
            const int pn = 2 * (c + 1);
            v2f nA0 = xA2[pn + 1], nA1 = xA2[pn + 2];
            v2f nB0 = xB2[pn + 1], nB1 = xB2[pn + 2];
            CMat CA, CB;
            build_C2(rb + 0 * PAIR_F, cA0, cB0, CA, CB);
            vecstep(cvA, c4A, CA); vecstep(cvB, c4B, CB);
            if (c < 9) {
                build_C2(rb + 1 * PAIR_F, cA1, cB1, CA, CB);
                vecstep(cvA, c4A, CA); vecstep(cvB, c4B, CB);
            }
            cA0 = nA0; cA1 = nA1; cB0 = nB0; cB1 = nB1;
        }
        clA[0] = cvA[0]; clA[1] = cvA[1]; clA[2] = cvA[2]; clA[3] = cvA[3]; clA[4] = c4A;
        clB[0] = cvB[0]; clB[1] = cvB[1]; clB[2] = cvB[2]; clB[3] = cvB[3]; clB[4] = c4B;

        __syncthreads();   // b1: phase-1 matrices ready (slots s=0..5 at k=s)
#pragma unroll 1
        for (int k = 0; k < 6; ++k) {
            float vA[5], vB[5];
#pragma unroll
            for (int r = 0; r < 5; ++r) {
                vA[r] = clA[0] * matbuf[k][r][lane];
                vB[r] = clB[0] * matbuf[k][r][lane + 64];
            }
#pragma unroll
            for (int l = 1; l < 5; ++l)
#pragma unroll
                for (int r = 0; r < 5; ++r) {
                    vA[r] = fmaf(clA[l], matbuf[k][l * 5 + r][lane],      vA[r]);
                    vB[r] = fmaf(clB[l], matbuf[k][l * 5 + r][lane + 64], vB[r]);
                }
#pragma unroll
            for (int r = 0; r < 5; ++r) { clA[r] = vA[r]; clB[r] = vB[r]; }
        }
        __syncthreads();   // b2
        __syncthreads();   // b3: phase-2 matrices ready (slots s=6..10 at k=s-6)
#pragma unroll 1
        for (int k = 0; k < 5; ++k) {
            float vA[5], vB[5];
#pragma unroll
            for (int r = 0; r < 5; ++r) {
                vA[r] = clA[0] * matbuf[k][r][lane];
                vB[r] = clB[0] * matbuf[k][r][lane + 64];
            }
#pragma unroll
            for (int l = 1; l < 5; ++l)
#pragma unroll
                for (int r = 0; r < 5; ++r) {
                    vA[r] = fmaf(clA[l], matbuf[k][l * 5 + r][lane],      vA[r]);
                    vB[r] = fmaf(clB[l], matbuf[k][l * 5 + r][lane + 64], vB[r]);
                }
#pragma unroll
            for (int r = 0; r < 5; ++r) { clA[r] = vA[r]; clB[r] = vB[r]; }
        }
        float* oA = out + (size_t)rowA * 5;                // vL stash (flat)
        float* oB = out + (size_t)rowB * 5;
#pragma unroll
        for (int i = 0; i < 5; ++i) { oA[i] = clA[i]; oB[i] = clB[i]; }
    } else {
        // ---- right vector wave: vlast, site 781, pairs 389..371 desc,
        //      then combine slots 10..0 (column form) ----
        v2f xAz = xA2[391], xBz = xB2[391];                // {x782, x783}
        float vlA[5], vlB[5], vnA[5], vnB[5];
#pragma unroll
        for (int l = 0; l < 5; ++l) {
            float base = core_last[2 * l], d = core_last[2 * l + 1] - base;
            vlA[l] = fmaf(xAz[1], d, base);
            vlB[l] = fmaf(xBz[1], d, base);
        }
        const float* cmL = cores_mid + (size_t)781 * 50;
#pragma unroll
        for (int l = 0; l < 5; ++l) {
            float aA = 0.f, aB = 0.f;
#pragma unroll
            for (int r = 0; r < 5; ++r) {
                float base = cmL[l * 10 + r], d = cmL[l * 10 + 5 + r] - base;
                aA = fmaf(fmaf(xAz[0], d, base), vlA[r], aA);
                aB = fmaf(fmaf(xBz[0], d, base), vlB[r], aB);
            }
            vnA[l] = aA; vnB[l] = aB;
        }
        v4f cvA = {vnA[0], vnA[1], vnA[2], vnA[3]};
        v4f cvB = {vnB[0], vnB[1], vnB[2], vnB[3]};
        float c4A = vnA[4], c4B = vnB[4];

        v4f sa;
        sload50(pk4 + (size_t)388 * PAIR_V, sa, lane);     // chunk0: pairs 388,389
        swrite50(buf0, sa, lane);
        sload50(pk4 + (size_t)386 * PAIR_V, sa, lane);
        v2f cA0 = xA2[390], cA1 = xA2[389];
        v2f cB0 = xB2[390], cB1 = xB2[389];

#pragma unroll 1
        for (int c = 0; c < 10; ++c) {                     // 9x2 + 1x1 = 19 pairs
            v4f* wb = (c & 1) ? buf0 : buf1;
            const float* rb = (const float*)((c & 1) ? buf1 : buf0);
            swrite50(wb, sa, lane);
            int ns = 388 - 2 * (c + 2);                    // >= 366, in bounds
            sload50(pk4 + (size_t)ns * PAIR_V, sa, lane);
            const int bn = 388 - 2 * (c + 1);
            v2f nA0 = xA2[bn + 2], nA1 = xA2[bn + 1];
            v2f nB0 = xB2[bn + 2], nB1 = xB2[bn + 1];
            CMat CA, CB;
            build_C2(rb + 1 * PAIR_F, cA0, cB0, CA, CB);   // pair 389-2c
            vecstep(cvA, c4A, CA); vecstep(cvB, c4B, CB);
            if (c < 9) {
                build_C2(rb + 0 * PAIR_F, cA1, cB1, CA, CB); // pair 388-2c
                vecstep(cvA, c4A, CA); vecstep(cvB, c4B, CB);
            }
            cA0 = nA0; cA1 = nA1; cB0 = nB0; cB1 = nB1;
        }
        float uA[5] = {cvA[0], cvA[1], cvA[2], cvA[3], c4A};
        float uB[5] = {cvB[0], cvB[1], cvB[2], cvB[3], c4B};

        __syncthreads();   // b1: phase-1 slots ready (s=10..5 at k=0..5)
#pragma unroll 1
        for (int k = 0; k < 6; ++k) {                      // u = M_s @ u
            float vA[5], vB[5];
#pragma unroll
            for (int i = 0; i < 5; ++i) {
                float aA = matbuf[k][i * 5][lane]      * uA[0];
                float aB = matbuf[k][i * 5][lane + 64] * uB[0];
#pragma unroll
                for (int l = 1; l < 5; ++l) {
                    aA = fmaf(matbuf[k][i * 5 + l][lane],      uA[l], aA);
                    aB = fmaf(matbuf[k][i * 5 + l][lane + 64], uB[l], aB);
                }
                vA[i] = aA; vB[i] = aB;
            }
#pragma unroll
            for (int i = 0; i < 5; ++i) { uA[i] = vA[i]; uB[i] = vB[i]; }
        }
        __syncthreads();   // b2
        __syncthreads();   // b3: phase-2 slots ready (s=4..0 at k=0..4)
#pragma unroll 1
        for (int k = 0; k < 5; ++k) {
            float vA[5], vB[5];
#pragma unroll
            for (int i = 0; i < 5; ++i) {
                float aA = matbuf[k][i * 5][lane]      * uA[0];
                float aB = matbuf[k][i * 5][lane + 64] * uB[0];
#pragma unroll
                for (int l = 1; l < 5; ++l) {
                    aA = fmaf(matbuf[k][i * 5 + l][lane],      uA[l], aA);
                    aB = fmaf(matbuf[k][i * 5 + l][lane + 64], uB[l], aB);
                }
                vA[i] = aA; vB[i] = aB;
            }
#pragma unroll
            for (int i = 0; i < 5; ++i) { uA[i] = vA[i]; uB[i] = vB[i]; }
        }
        float* oA = out + WROFF + (size_t)rowA * 5;        // wR stash (flat)
        float* oB = out + WROFF + (size_t)rowB * 5;
#pragma unroll
        for (int i = 0; i < 5; ++i) { oA[i] = uA[i]; oB[i] = uB[i]; }
    }
}

// ---- stage 2a: res[r] = vL . wR (res overwrites dead pk region of ws) ----
__global__ __launch_bounds__(256)
void finish_dot(const float* __restrict__ outF, float* __restrict__ res)
{
    int r = blockIdx.x * 256 + threadIdx.x;
    const float* vl = outF + (size_t)r * 5;
    const float* wr = outF + WROFF + (size_t)r * 5;
    float s = vl[0] * wr[0];
#pragma unroll
    for (int i = 1; i < 5; ++i) s = fmaf(vl[i], wr[i], s);
    res[r] = s;
}

// ---- stage 2b: out = res*fc_w + fc_b ----
__global__ __launch_bounds__(256)
void finish_out(const float* __restrict__ res, const float* __restrict__ fc_w,
                const float* __restrict__ fc_b, float* __restrict__ out)
{
    int r = blockIdx.x * 256 + threadIdx.x;
    float rv = res[r];
    float* o = out + (size_t)r * NOUT;
#pragma unroll
    for (int j = 0; j < NOUT; ++j) o[j] = fmaf(rv, fc_w[j], fc_b[j]);
}

extern "C" void kernel_launch(void* const* d_in, const int* in_sizes, int n_in,
                              void* d_out, int out_size, void* d_ws, size_t ws_size,
                              hipStream_t stream) {
    const float* x          = (const float*)d_in[0];
    const float* core_first = (const float*)d_in[1];
    const float* cores_mid  = (const float*)d_in[2];
    const float* core_last  = (const float*)d_in[3];
    const float* fc_w       = (const float*)d_in[4];
    const float* fc_b       = (const float*)d_in[5];
    float* out              = (float*)d_out;
    float* pk               = (float*)d_ws;   // 390*100*4 = 156,000 B
    float* res              = (float*)d_ws;   // reuses pk region (dead after main)

    hipLaunchKernelGGL(prepack_pairs, dim3((NPAIR * 100 + 255) / 256), dim3(256),
                       0, stream, cores_mid, pk);
    hipLaunchKernelGGL(mps_half_kernel, dim3(256), dim3(768), 0, stream,
                       x, core_first, cores_mid, core_last, pk, out);
    hipLaunchKernelGGL(finish_dot, dim3(Bn / 256), dim3(256), 0, stream,
                       out, res);
    hipLaunchKernelGGL(finish_out, dim3(Bn / 256), dim3(256), 0, stream,
                       res, fc_w, fc_b, out);
}

// Round 4
// 125.034 us; speedup vs baseline: 4.1692x; 4.1692x over previous
//
#include <hip/hip_runtime.h>

// MPS tensor-train classifier, B=16384, D=784, BOND=5, OUT=10.
//
// Round-7: revert to round-1 structure (best: 46.9 us, no spills), replace
// the LDS-broadcast coefficient path with SCALAR (SGPR) loads.
// Rationale: pair coefficients are wave-uniform; round-1 saturated the LDS
// pipe (10,920 broadcast ds_read_b128/CU ~ 131k cyc >= kernel duration)
// delivering identical bytes to all 64 lanes. With readfirstlane-forced
// uniform addresses the compiler emits s_load_dwordx4 -> SGPRs; each v_fma
// uses the coefficient as its single SGPR operand. No pkbuf, no staging
// loops, no double-buffer barriers. VGPR pressure drops (coefficients never
// touch VGPRs) - l-major matstep live set ~70 floats (round-5/6's dual-row
// ~150-float state caused catastrophic scratch placement: 921 MB writes).
//
// 256 blocks x 1024 thr (16 waves), lane = batch row. Wave 0: fwd vector
// chain (site 0 + pairs 0..40). Waves 1..14: 22-pair matrix products.
// Wave 15: bwd (pairs 389..349 desc, stored transposed, + site 781).
// Combine via LDS matbuf (2 phases, 3 barriers) exactly as round-1.
//
// pk layout (100 floats/pair), q = 0..3 (coeff of 1, xa, xb, xa*xb):
//   rows:  q*20 + l*4 + r   (l=0..4, r=0..3)      -> s4[q*5 + l]
//   col4:  80 + l*4 + q     (l=0..3, q=0..3)      -> s4[20 + l]  (l-major!)
//   (4,4): 96 + q                                  -> s4[24]

typedef float v4f __attribute__((ext_vector_type(4)));
typedef float v2f __attribute__((ext_vector_type(2)));

constexpr int Bn     = 16384;
constexpr int Dn     = 784;
constexpr int NOUT   = 10;
constexpr int NPAIR  = 390;   // pairs cover sites 1..780
constexpr int PFV    = 41;    // fwd pairs 0..40
constexpr int PMAT   = 22;    // pairs per matrix wave (14 waves: 41..348)
constexpr int BWD_P0 = 349;   // bwd pairs 349..389 (stored transposed)
constexpr int PAIR_F = 100;   // floats per pair block

__device__ __forceinline__ v4f splat4(float x) { v4f v = {x, x, x, x}; return v; }
__device__ __forceinline__ v4f fma4(v4f a, v4f b, v4f c) {
    return __builtin_elementwise_fma(a, b, c);
}

struct Frag { v4f r[5]; float c4[5]; };          // 5x5 running product

// T = M @ C(s; xa,xb), l-major: C row l is built (from uniform/SGPR
// coefficients) and immediately consumed, never 25 floats live at once.
__device__ __forceinline__ void matstepLM(const Frag& M, Frag& T,
                                          const float* __restrict__ s, v2f xc) {
    const float xa = xc[0], xb = xc[1], xab = xa * xb;
    const v4f va = splat4(xa), vb = splat4(xb), vp = splat4(xab);
    const v4f* s4 = (const v4f*)s;
#pragma unroll
    for (int l = 0; l < 5; ++l) {
        v4f crow = fma4(vp, s4[15 + l], fma4(vb, s4[10 + l], fma4(va, s4[5 + l], s4[l])));
        v4f cq = (l < 4) ? s4[20 + l] : s4[24];
        float c4l = fmaf(xab, cq[3], fmaf(xb, cq[2], fmaf(xa, cq[1], cq[0])));
#pragma unroll
        for (int i = 0; i < 5; ++i) {
            float mil = (l < 4) ? M.r[i][l] : M.c4[i];
            if (l == 0) {
                T.r[i]  = splat4(mil) * crow;
                T.c4[i] = mil * c4l;
            } else {
                T.r[i]  = fma4(splat4(mil), crow, T.r[i]);
                T.c4[i] = fmaf(mil, c4l, T.c4[i]);
            }
        }
    }
}

// c' = c @ C (row vector), l-major
__device__ __forceinline__ void vecstepLM(v4f& cv, float& c4,
                                          const float* __restrict__ s, v2f xc) {
    const float xa = xc[0], xb = xc[1], xab = xa * xb;
    const v4f va = splat4(xa), vb = splat4(xb), vp = splat4(xab);
    const v4f* s4 = (const v4f*)s;
    v4f acc; float a4;
#pragma unroll
    for (int l = 0; l < 5; ++l) {
        v4f crow = fma4(vp, s4[15 + l], fma4(vb, s4[10 + l], fma4(va, s4[5 + l], s4[l])));
        v4f cq = (l < 4) ? s4[20 + l] : s4[24];
        float c4l = fmaf(xab, cq[3], fmaf(xb, cq[2], fmaf(xa, cq[1], cq[0])));
        float cl = (l < 4) ? cv[l] : c4;
        if (l == 0) { acc = splat4(cl) * crow; a4 = cl * c4l; }
        else        { acc = fma4(splat4(cl), crow, acc); a4 = fmaf(cl, c4l, a4); }
    }
    cv = acc; c4 = a4;
}

// ---- prepack: build pair blocks (transposed for p >= BWD_P0) ----
// cores_mid element (m,l,i,k) at (m*5+l)*10 + i*5 + k
__global__ void prepack_pairs(const float* __restrict__ cm, float* __restrict__ pk)
{
    int idx = blockIdx.x * 256 + threadIdx.x;
    if (idx >= NPAIR * 100) return;
    int p = idx / 100, rest = idx - p * 100;
    int q = rest / 25, e = rest - q * 25;
    int l = e / 5, r = e - l * 5;
    int m1 = 2 * p + 1, m2 = 2 * p + 2;
    const float* L = cm + (size_t)(m1 * 5 + l) * 10;
    float acc = 0.f;
#pragma unroll
    for (int k = 0; k < 5; ++k) {
        float Lk = (q & 1) ? (L[5 + k] - L[k]) : L[k];
        const float* R = cm + (size_t)(m2 * 5 + k) * 10;
        float Rk = (q & 2) ? (R[5 + r] - R[r]) : R[r];
        acc = fmaf(Lk, Rk, acc);
    }
    int wl = l, wr = r;
    if (p >= BWD_P0) { wl = r; wr = l; }   // store C^T for bwd wave
    int off;
    if (wr < 4)      off = q * 20 + wl * 4 + wr;
    else if (wl < 4) off = 80 + wl * 4 + q;   // col4, l-major
    else             off = 96 + q;            // c44 quad
    pk[(size_t)p * PAIR_F + off] = acc;
}

__global__ __launch_bounds__(1024, 4)
void mps_pair_kernel(const float* __restrict__ x,          // [B, D]
                     const float* __restrict__ core_first, // [2,5]
                     const float* __restrict__ cores_mid,  // [782,5,2,5]
                     const float* __restrict__ core_last,  // [5,2]
                     const float* __restrict__ fc_w,       // [10]
                     const float* __restrict__ fc_b,       // [10]
                     const float* __restrict__ pk,         // [390][100]
                     float* __restrict__ out)              // [B,10]
{
    __shared__ float matbuf[7][25][64];   // 44.8 KB combine matrices
    __shared__ float bv[5][64];           // backward vectors

    const int lane = threadIdx.x & 63;
    const int wave = threadIdx.x >> 6;
    const int wu   = __builtin_amdgcn_readfirstlane(wave);  // uniform wave id
    const int row  = blockIdx.x * 64 + lane;
    const float* __restrict__ xr = x + (size_t)row * Dn;
    const v2f* __restrict__ xr2 = (const v2f*)xr;          // 392 entries

    if (wu >= 1 && wu <= 14) {
        // ---- matrix wave: 22 pairs, scalar-coefficient matsteps ----
        const int p0 = PFV + PMAT * (wu - 1);              // uniform

        Frag M, T;
        M.r[0] = {1,0,0,0}; M.r[1] = {0,1,0,0}; M.r[2] = {0,0,1,0};
        M.r[3] = {0,0,0,1}; M.r[4] = {0,0,0,0};
        M.c4[0] = 0; M.c4[1] = 0; M.c4[2] = 0; M.c4[3] = 0; M.c4[4] = 1;

        v2f x0 = xr2[p0 + 1], x1 = xr2[p0 + 2];
#pragma unroll 1
        for (int j = 0; j < PMAT; j += 2) {
            const float* s0 = pk + (size_t)(p0 + j) * PAIR_F;  // uniform addr
            v2f nx0 = xr2[p0 + j + 3], nx1 = xr2[p0 + j + 4];  // x prefetch
            matstepLM(M, T, s0, x0);
            matstepLM(T, M, s0 + PAIR_F, x1);
            x0 = nx0; x1 = nx1;
        }

        if (wu <= 7) {
#pragma unroll
            for (int i = 0; i < 5; ++i) {
#pragma unroll
                for (int r = 0; r < 4; ++r) matbuf[wu - 1][i * 5 + r][lane] = M.r[i][r];
                matbuf[wu - 1][i * 5 + 4][lane] = M.c4[i];
            }
        }
        __syncthreads();   // b1
        __syncthreads();   // b2
        if (wu >= 8) {
#pragma unroll
            for (int i = 0; i < 5; ++i) {
#pragma unroll
                for (int r = 0; r < 4; ++r) matbuf[wu - 8][i * 5 + r][lane] = M.r[i][r];
                matbuf[wu - 8][i * 5 + 4][lane] = M.c4[i];
            }
        }
        __syncthreads();   // b3
    } else if (wu == 0) {
        // ---- forward: carry0, site 0 (scalar), pairs 0..40, combine ----
        v2f x01 = xr2[0];
        float cl[5], cn[5];
#pragma unroll
        for (int r = 0; r < 5; ++r)
            cl[r] = fmaf(x01[0], core_first[5 + r] - core_first[r], core_first[r]);
        const float* cm0 = cores_mid;                      // site 0
#pragma unroll
        for (int r = 0; r < 5; ++r) {
            float a = 0.f;
#pragma unroll
            for (int l = 0; l < 5; ++l) {
                float m = fmaf(x01[1], cm0[l * 10 + 5 + r] - cm0[l * 10 + r], cm0[l * 10 + r]);
                a = fmaf(cl[l], m, a);
            }
            cn[r] = a;
        }
        v4f cv = {cn[0], cn[1], cn[2], cn[3]};
        float c4 = cn[4];

        v2f xc = xr2[1];
#pragma unroll 1
        for (int p = 0; p < PFV; ++p) {
            v2f nx = xr2[p + 2];
            vecstepLM(cv, c4, pk + (size_t)p * PAIR_F, xc);
            xc = nx;
        }
        cl[0] = cv[0]; cl[1] = cv[1]; cl[2] = cv[2]; cl[3] = cv[3]; cl[4] = c4;

        __syncthreads();   // b1: phase-1 matrices ready
#pragma unroll 1
        for (int w2 = 0; w2 < 7; ++w2) {
            float v0[5];
#pragma unroll
            for (int r = 0; r < 5; ++r) v0[r] = cl[0] * matbuf[w2][r][lane];
#pragma unroll
            for (int l = 1; l < 5; ++l)
#pragma unroll
                for (int r = 0; r < 5; ++r)
                    v0[r] = fmaf(cl[l], matbuf[w2][l * 5 + r][lane], v0[r]);
#pragma unroll
            for (int r = 0; r < 5; ++r) cl[r] = v0[r];
        }
        __syncthreads();   // b2
        __syncthreads();   // b3: phase-2 matrices + bv ready
#pragma unroll 1
        for (int w2 = 0; w2 < 7; ++w2) {
            float v0[5];
#pragma unroll
            for (int r = 0; r < 5; ++r) v0[r] = cl[0] * matbuf[w2][r][lane];
#pragma unroll
            for (int l = 1; l < 5; ++l)
#pragma unroll
                for (int r = 0; r < 5; ++r)
                    v0[r] = fmaf(cl[l], matbuf[w2][l * 5 + r][lane], v0[r]);
#pragma unroll
            for (int r = 0; r < 5; ++r) cl[r] = v0[r];
        }
        float res = 0.f;
#pragma unroll
        for (int l = 0; l < 5; ++l) res = fmaf(cl[l], bv[l][lane], res);
        float* orow = out + (size_t)row * NOUT;
#pragma unroll
        for (int o = 0; o < NOUT; ++o) orow[o] = fmaf(res, fc_w[o], fc_b[o]);
    } else {
        // ---- backward: vlast, site 781 (scalar), pairs 389..349 desc ----
        v2f xz = xr2[391];                                 // {x782, x783}
        float vl[5], vn[5];
#pragma unroll
        for (int l = 0; l < 5; ++l)
            vl[l] = fmaf(xz[1], core_last[2 * l + 1] - core_last[2 * l], core_last[2 * l]);
        const float* cmL = cores_mid + (size_t)781 * 50;
#pragma unroll
        for (int l = 0; l < 5; ++l) {
            float a = 0.f;
#pragma unroll
            for (int r = 0; r < 5; ++r) {
                float m = fmaf(xz[0], cmL[l * 10 + 5 + r] - cmL[l * 10 + r], cmL[l * 10 + r]);
                a = fmaf(m, vl[r], a);
            }
            vn[l] = a;
        }
        v4f cv = {vn[0], vn[1], vn[2], vn[3]};
        float c4 = vn[4];

        v2f xc = xr2[390];
#pragma unroll 1
        for (int p = 389; p >= BWD_P0; --p) {              // transposed storage
            v2f nx = xr2[p];                               // x for pair p-1
            vecstepLM(cv, c4, pk + (size_t)p * PAIR_F, xc);
            xc = nx;
        }

        __syncthreads();   // b1
        __syncthreads();   // b2
        bv[0][lane] = cv[0]; bv[1][lane] = cv[1]; bv[2][lane] = cv[2];
        bv[3][lane] = cv[3]; bv[4][lane] = c4;
        __syncthreads();   // b3
    }
}

extern "C" void kernel_launch(void* const* d_in, const int* in_sizes, int n_in,
                              void* d_out, int out_size, void* d_ws, size_t ws_size,
                              hipStream_t stream) {
    const float* x          = (const float*)d_in[0];
    const float* core_first = (const float*)d_in[1];
    const float* cores_mid  = (const float*)d_in[2];
    const float* core_last  = (const float*)d_in[3];
    const float* fc_w       = (const float*)d_in[4];
    const float* fc_b       = (const float*)d_in[5];
    float* out              = (float*)d_out;
    float* pk               = (float*)d_ws;   // 390*100*4 = 156,000 B

    hipLaunchKernelGGL(prepack_pairs, dim3((NPAIR * 100 + 255) / 256), dim3(256),
                       0, stream, cores_mid, pk);
    hipLaunchKernelGGL(mps_pair_kernel, dim3(Bn / 64), dim3(1024), 0, stream,
                       x, core_first, cores_mid, core_last, fc_w, fc_b, pk, out);
}